// Round 9
// baseline (2044.172 us; speedup 1.0000x reference)
//
#include <hip/hip_runtime.h>
#include <hip/hip_fp16.h>

// CRF mean-field, NHWC. Per iter: out = x + sw * blurW(blurH(softmax_C(xc)))
//
// R9 = R7 (proven 127 us/dispatch) + ONE change: P2 softmax input uses
// aligned-window float4 loads + register rotate instead of 21 scalar loads.
//   g = pixel float index; a0 = g & ~3 (16B-aligned); k = g & 3.
//   6x float4 from a0 covers floats g..g+20 for any k (a0+24 <= NTOT always:
//   max valid g = NTOT-21 -> a0 = NTOT-24). Rotate the 24-reg window left
//   by k via two cndmask stages (45 selects, compile-time indices only).
//   TA: 6 wave-load-instrs/pixel-row vs 21 -> ~3x fewer line-touch cycles
//   on the phase that oversubscribed the TA pipe (R7: ~570K line-cycles/CU
//   vs 305K wall; VALU 48%, HBM 39%, occ 56% all unsaturated).
// R8's LDS-scatter transpose attempt cost +43us VALU; this costs ~7us.
//
// Everything else verbatim R7: XCD bijective swizzle (FETCH 244->194MB),
// planar channel-pair fp16 LDS, packed v_pk_fma_f16 blurs in place,
// float4 P5 epilogue with planar b16 gather walk.
//
// In-place safety: P2 pixel-private, P3 column-private, P4 row-private
// (all taps in registers before any write); 3 barriers total.

#define BB    16
#define Himg  384
#define Wimg  384
#define CC    21
#define NP    11                   // channel pairs (last = c20 + zero pad)
#define TH    16
#define TW    16
#define RR    4
#define PH    (TH + 2*RR)          // 24
#define PW    (TW + 2*RR)          // 24
#define NPIX  (PH * PW)            // 576
#define PLANE_B 2384               // plane stride bytes (2304 + 80 pad; /4 %32 = 20)
#define ROW_B   (PW * 4)           // 96 B per plane row (24 slots)
#define NTASK (PW * NP)            // 264 (col, plane) tasks
#define RCHUNKS (TW * CC / 4)      // 84 float4 per tile row
#define NCHUNK5 (TH * RCHUNKS)     // 1344 output chunks
#define NTOT  (BB * Himg * Wimg * CC)  // 49545216
#define NTILES  (24 * 24 * BB)     // 9216

static __device__ __forceinline__ unsigned int pk_add(unsigned int a, unsigned int b) {
    unsigned int d; asm("v_pk_add_f16 %0, %1, %2" : "=v"(d) : "v"(a), "v"(b)); return d;
}
static __device__ __forceinline__ unsigned int pk_mul(unsigned int a, unsigned int b) {
    unsigned int d; asm("v_pk_mul_f16 %0, %1, %2" : "=v"(d) : "v"(a), "v"(b)); return d;
}
static __device__ __forceinline__ unsigned int pk_fma(unsigned int a, unsigned int b, unsigned int c) {
    unsigned int d; asm("v_pk_fma_f16 %0, %1, %2, %3" : "=v"(d) : "v"(a), "v"(b), "v"(c)); return d;
}

__global__ __launch_bounds__(256, 6)
void crf_iter_kernel(const float* __restrict__ xin,
                     const float* __restrict__ unary,
                     float* __restrict__ out,
                     const float* __restrict__ spacings,
                     const float* __restrict__ inv_theta,
                     const float* __restrict__ sw_ptr)
{
    __shared__ __align__(16) unsigned char smem[NP * PLANE_B];  // 26224 B

    const int tid = threadIdx.x;

    // ---- XCD-aware bijective swizzle: each XCD gets 1152 contiguous tiles ----
    const int lin = blockIdx.x + 24 * (blockIdx.y + 24 * blockIdx.z);
    const int swz = (lin & 7) * (NTILES / 8) + (lin >> 3);
    const int b   = swz / 576;
    const int rem = swz - b * 576;
    const int ty  = rem / 24;
    const int h0  = ty * TH;
    const int w0  = (rem - ty * 24) * TW;

    const float sp_h = spacings[b * 2 + 0];
    const float sp_w = spacings[b * 2 + 1];
    const float ith  = inv_theta[0];
    const float itw  = inv_theta[1];
    const float sw   = sw_ptr[0];
    // symmetric taps: k[i] == k[8-i]; center (i==4) excluded. Keep 4 each.
    unsigned int khp[4], kwp[4];
#pragma unroll
    for (int i = 0; i < 4; ++i) {
        float dh = sp_h * (float)(i - 4) * ith;
        float dw = sp_w * (float)(i - 4) * itw;
        float kh = __expf(-0.5f * dh * dh);
        float kw = sw * __expf(-0.5f * dw * dw);   // fold sw into horizontal
        __half2 a = __floats2half2_rn(kh, kh);
        __half2 c = __floats2half2_rn(kw, kw);
        khp[i] = *(unsigned int*)&a;
        kwp[i] = *(unsigned int*)&c;
    }

    // ---- Phase 2 (fused stage+softmax): global -> regs -> planar LDS ----
    for (int p = tid; p < NPIX; p += 256) {
        const int r  = p / PW;
        const int px = p - r * PW;
        const int hh = h0 - RR + r;
        const int gw = w0 - RR + px;
        // planar slot: addr/4 = p + plane*596 -> consecutive lanes,
        // consecutive banks: conflict-free.
        unsigned char* lbase = smem + p * 4;
        if (hh >= 0 && hh < Himg && gw >= 0 && gw < Wimg) {
            const int gidx = ((b * Himg + hh) * Wimg + gw) * CC;  // float idx
            const int a0   = gidx & ~3;        // 16B-aligned window start
            const int k    = gidx & 3;         // rotate amount 0..3
            float v[24];
#pragma unroll
            for (int j = 0; j < 6; ++j) {      // 6 aligned float4 loads
                const float4 q = *(const float4*)(xin + a0 + 4 * j);
                v[4*j+0] = q.x; v[4*j+1] = q.y; v[4*j+2] = q.z; v[4*j+3] = q.w;
            }
            const bool s1 = (k & 1) != 0;
            const bool s2 = (k & 2) != 0;
#pragma unroll
            for (int i = 0; i < 23; ++i) v[i] = s1 ? v[i+1] : v[i];
#pragma unroll
            for (int i = 0; i < 21; ++i) v[i] = s2 ? v[i+2] : v[i];
            // v[0..20] now hold the pixel's 21 channel logits.
            float m = v[0];
#pragma unroll
            for (int c = 1; c < CC; ++c) m = fmaxf(m, v[c]);
            float s = 0.f;
#pragma unroll
            for (int c = 0; c < CC; ++c) { v[c] = __expf(v[c] - m); s += v[c]; }
            const float inv = 1.0f / s;
#pragma unroll
            for (int cp = 0; cp < 10; ++cp) {
                __half2 hx = __floats2half2_rn(v[2*cp] * inv, v[2*cp+1] * inv);
                *(__half2*)(lbase + cp * PLANE_B) = hx;
            }
            __half2 hl = __floats2half2_rn(v[20] * inv, 0.f);  // pad slot = 0
            *(__half2*)(lbase + 10 * PLANE_B) = hl;
        } else {
            const __half2 z = __floats2half2_rn(0.f, 0.f);
#pragma unroll
            for (int cp = 0; cp < NP; ++cp)
                *(__half2*)(lbase + cp * PLANE_B) = z;
        }
    }
    __syncthreads();

    // ---- Phase 3: vertical blur, packed fp16, in place (rows 0..15) ----
    for (int t = tid; t < NTASK; t += 256) {
        const int cp  = t / PW;
        const int col = t - cp * PW;
        unsigned char* base = smem + cp * PLANE_B + col * 4;
        unsigned int v[PH];
#pragma unroll
        for (int r = 0; r < PH; ++r) v[r] = *(const unsigned int*)(base + r * ROW_B);
#pragma unroll
        for (int tt = 0; tt < TH; ++tt) {
            unsigned int s0 = pk_add(v[tt],     v[tt + 8]);
            unsigned int s1 = pk_add(v[tt + 1], v[tt + 7]);
            unsigned int s2 = pk_add(v[tt + 2], v[tt + 6]);
            unsigned int s3 = pk_add(v[tt + 3], v[tt + 5]);
            unsigned int acc = pk_mul(khp[0], s0);
            acc = pk_fma(khp[1], s1, acc);
            acc = pk_fma(khp[2], s2, acc);
            acc = pk_fma(khp[3], s3, acc);
            *(unsigned int*)(base + tt * ROW_B) = acc;
        }
    }
    __syncthreads();

    // ---- Phase 4: horizontal blur * sw, b128 rows, in place (cols 0..15) ----
    if (tid < TH * NP) {                   // 176 tasks
        const int h  = tid / NP;
        const int cp = tid - h * NP;
        unsigned char* base = smem + cp * PLANE_B + h * ROW_B;
        unsigned int v[PW];
#pragma unroll
        for (int k = 0; k < 6; ++k) {
            const uint4 q = *(const uint4*)(base + k * 16);
            v[4*k+0] = q.x; v[4*k+1] = q.y; v[4*k+2] = q.z; v[4*k+3] = q.w;
        }
        unsigned int o[TW];
#pragma unroll
        for (int wt = 0; wt < TW; ++wt) {
            unsigned int s0 = pk_add(v[wt],     v[wt + 8]);
            unsigned int s1 = pk_add(v[wt + 1], v[wt + 7]);
            unsigned int s2 = pk_add(v[wt + 2], v[wt + 6]);
            unsigned int s3 = pk_add(v[wt + 3], v[wt + 5]);
            unsigned int acc = pk_mul(kwp[0], s0);
            acc = pk_fma(kwp[1], s1, acc);
            acc = pk_fma(kwp[2], s2, acc);
            acc = pk_fma(kwp[3], s3, acc);
            o[wt] = acc;
        }
#pragma unroll
        for (int k = 0; k < 4; ++k) {
            uint4 wq;
            wq.x = o[4*k+0]; wq.y = o[4*k+1]; wq.z = o[4*k+2]; wq.w = o[4*k+3];
            *(uint4*)(base + k * 16) = wq;
        }
    }
    __syncthreads();

    // ---- Phase 5: out = unary + s, float4 I/O, planar b16 walk ----
    // s lives at planar rows 0..15 (h), cols 0..15 (wt). Walk per chunk:
    //   (px, even c<20) -> +2 ; (px, odd c) -> +(PLANE_B-2) ;
    //   (px, 20) -> (px+1, 0): +(4 - 10*PLANE_B).
    {
        const int gbase = ((b * Himg + h0) * Wimg + w0) * CC;
        for (int j = tid; j < NCHUNK5; j += 256) {
            const int hrow = j / RCHUNKS;
            const int qq   = j - hrow * RCHUNKS;
            const int f    = qq * 4;
            int px = f / 21;
            int c  = f - px * 21;
            int addr = (c >> 1) * PLANE_B + hrow * ROW_B + px * 4 + (c & 1) * 2;
            float sv[4];
#pragma unroll
            for (int i = 0; i < 4; ++i) {
                sv[i] = __half2float(*(const __half*)(smem + addr));
                const int wrap = (c == 20);
                const int odd  = c & 1;
                addr += wrap ? (4 - 10 * PLANE_B) : (odd ? (PLANE_B - 2) : 2);
                c = wrap ? 0 : c + 1;
            }
            const int g = gbase + hrow * (Wimg * CC) + f;
            const float4 u = *(const float4*)(unary + g);
            float4 o;
            o.x = u.x + sv[0]; o.y = u.y + sv[1];
            o.z = u.z + sv[2]; o.w = u.w + sv[3];
            *(float4*)(out + g) = o;
        }
    }
}

extern "C" void kernel_launch(void* const* d_in, const int* in_sizes, int n_in,
                              void* d_out, int out_size, void* d_ws, size_t ws_size,
                              hipStream_t stream) {
    const float* x         = (const float*)d_in[0];
    const float* spacings  = (const float*)d_in[1];
    const float* sw        = (const float*)d_in[2];
    const float* inv_theta = (const float*)d_in[3];
    float* out = (float*)d_out;
    float* ws  = (float*)d_ws;

    dim3 grid(Wimg / TW, Himg / TH, BB);   // 24 x 24 x 16 = 9216 blocks
    dim3 block(256);

    crf_iter_kernel<<<grid, block, 0, stream>>>(x,   x, out, spacings, inv_theta, sw);
    crf_iter_kernel<<<grid, block, 0, stream>>>(out, x, ws,  spacings, inv_theta, sw);
    crf_iter_kernel<<<grid, block, 0, stream>>>(ws,  x, out, spacings, inv_theta, sw);
    crf_iter_kernel<<<grid, block, 0, stream>>>(out, x, ws,  spacings, inv_theta, sw);
    crf_iter_kernel<<<grid, block, 0, stream>>>(ws,  x, out, spacings, inv_theta, sw);
}

// Round 10
// 810.246 us; speedup vs baseline: 2.5229x; 2.5229x over previous
//
#include <hip/hip_runtime.h>
#include <hip/hip_fp16.h>

// CRF mean-field, NHWC. Per iter: out = x + sw * blurW(blurH(softmax_C(xc)))
//
// R10 = R7 (proven 127 us/dispatch) + P2 input via 6 aligned float4 loads
// + register rotate, implemented with NAMED SCALARS.
// R9 tried this with float v[24] + shift loops -> compiler demoted the
// array to scratch (WRITE_SIZE 193->842 MB, VALU 17%, 375 us). Named
// scalar SSA chains (t0..t23 -> b0..b22 -> v[0..20]) cannot be demoted;
// final v[21] with constant indices is R7-proven register-resident.
//   g = pixel float index; a0 = g & ~3 (16B-aligned); k = g & 3.
//   6 float4 from a0 cover floats g..g+20 for any k; max a0+24 == NTOT.
//   rotate left by k: stage1 (k&1): b_i = s1 ? t_{i+1} : t_i (23 selects);
//   stage2 (k&2): v_i = s2 ? b_{i+2} : b_i (21 selects). 44 cndmask/pixel.
//   TA: 6 wave-load-instrs/pixel vs 21 scalar -> ~3.5x fewer line-touches
//   on the phase that oversubscribes the TA pipe (R7: VALU 48, HBM 39,
//   occ 56 all unsaturated at 2x the HBM floor).
//
// Everything else verbatim R7: XCD bijective swizzle (FETCH 244->194MB),
// planar channel-pair fp16 LDS, packed v_pk_fma_f16 blurs in place,
// float4 P5 epilogue with planar b16 gather walk.
//
// In-place safety: P2 pixel-private, P3 column-private, P4 row-private
// (all taps in registers before any write); 3 barriers total.

#define BB    16
#define Himg  384
#define Wimg  384
#define CC    21
#define NP    11                   // channel pairs (last = c20 + zero pad)
#define TH    16
#define TW    16
#define RR    4
#define PH    (TH + 2*RR)          // 24
#define PW    (TW + 2*RR)          // 24
#define NPIX  (PH * PW)            // 576
#define PLANE_B 2384               // plane stride bytes (2304 + 80 pad; /4 %32 = 20)
#define ROW_B   (PW * 4)           // 96 B per plane row (24 slots)
#define NTASK (PW * NP)            // 264 (col, plane) tasks
#define RCHUNKS (TW * CC / 4)      // 84 float4 per tile row
#define NCHUNK5 (TH * RCHUNKS)     // 1344 output chunks
#define NTOT  (BB * Himg * Wimg * CC)  // 49545216 (divisible by 4)
#define NTILES  (24 * 24 * BB)     // 9216

static __device__ __forceinline__ unsigned int pk_add(unsigned int a, unsigned int b) {
    unsigned int d; asm("v_pk_add_f16 %0, %1, %2" : "=v"(d) : "v"(a), "v"(b)); return d;
}
static __device__ __forceinline__ unsigned int pk_mul(unsigned int a, unsigned int b) {
    unsigned int d; asm("v_pk_mul_f16 %0, %1, %2" : "=v"(d) : "v"(a), "v"(b)); return d;
}
static __device__ __forceinline__ unsigned int pk_fma(unsigned int a, unsigned int b, unsigned int c) {
    unsigned int d; asm("v_pk_fma_f16 %0, %1, %2, %3" : "=v"(d) : "v"(a), "v"(b), "v"(c)); return d;
}

__global__ __launch_bounds__(256, 6)
void crf_iter_kernel(const float* __restrict__ xin,
                     const float* __restrict__ unary,
                     float* __restrict__ out,
                     const float* __restrict__ spacings,
                     const float* __restrict__ inv_theta,
                     const float* __restrict__ sw_ptr)
{
    __shared__ __align__(16) unsigned char smem[NP * PLANE_B];  // 26224 B

    const int tid = threadIdx.x;

    // ---- XCD-aware bijective swizzle: each XCD gets 1152 contiguous tiles ----
    const int lin = blockIdx.x + 24 * (blockIdx.y + 24 * blockIdx.z);
    const int swz = (lin & 7) * (NTILES / 8) + (lin >> 3);
    const int b   = swz / 576;
    const int rem = swz - b * 576;
    const int ty  = rem / 24;
    const int h0  = ty * TH;
    const int w0  = (rem - ty * 24) * TW;

    const float sp_h = spacings[b * 2 + 0];
    const float sp_w = spacings[b * 2 + 1];
    const float ith  = inv_theta[0];
    const float itw  = inv_theta[1];
    const float sw   = sw_ptr[0];
    // symmetric taps: k[i] == k[8-i]; center (i==4) excluded. Keep 4 each.
    unsigned int khp[4], kwp[4];
#pragma unroll
    for (int i = 0; i < 4; ++i) {
        float dh = sp_h * (float)(i - 4) * ith;
        float dw = sp_w * (float)(i - 4) * itw;
        float kh = __expf(-0.5f * dh * dh);
        float kw = sw * __expf(-0.5f * dw * dw);   // fold sw into horizontal
        __half2 a = __floats2half2_rn(kh, kh);
        __half2 c = __floats2half2_rn(kw, kw);
        khp[i] = *(unsigned int*)&a;
        kwp[i] = *(unsigned int*)&c;
    }

    // ---- Phase 2 (fused stage+softmax): global -> regs -> planar LDS ----
    for (int p = tid; p < NPIX; p += 256) {
        const int r  = p / PW;
        const int px = p - r * PW;
        const int hh = h0 - RR + r;
        const int gw = w0 - RR + px;
        // planar slot: addr/4 = p + plane*596 -> consecutive lanes,
        // consecutive banks: conflict-free.
        unsigned char* lbase = smem + p * 4;
        if (hh >= 0 && hh < Himg && gw >= 0 && gw < Wimg) {
            const int gidx = ((b * Himg + hh) * Wimg + gw) * CC;  // float idx
            const int a0   = gidx & ~3;        // 16B-aligned window start
            const int k    = gidx & 3;         // rotate amount 0..3
            const float4 q0 = *(const float4*)(xin + a0);
            const float4 q1 = *(const float4*)(xin + a0 + 4);
            const float4 q2 = *(const float4*)(xin + a0 + 8);
            const float4 q3 = *(const float4*)(xin + a0 + 12);
            const float4 q4 = *(const float4*)(xin + a0 + 16);
            const float4 q5 = *(const float4*)(xin + a0 + 20);
            const float t0  = q0.x, t1  = q0.y, t2  = q0.z, t3  = q0.w;
            const float t4  = q1.x, t5  = q1.y, t6  = q1.z, t7  = q1.w;
            const float t8  = q2.x, t9  = q2.y, t10 = q2.z, t11 = q2.w;
            const float t12 = q3.x, t13 = q3.y, t14 = q3.z, t15 = q3.w;
            const float t16 = q4.x, t17 = q4.y, t18 = q4.z, t19 = q4.w;
            const float t20 = q5.x, t21 = q5.y, t22 = q5.z, t23 = q5.w;
            const bool s1 = (k & 1) != 0;
            const bool s2 = (k & 2) != 0;
            const float b0  = s1 ? t1  : t0,  b1  = s1 ? t2  : t1;
            const float b2  = s1 ? t3  : t2,  b3  = s1 ? t4  : t3;
            const float b4  = s1 ? t5  : t4,  b5  = s1 ? t6  : t5;
            const float b6  = s1 ? t7  : t6,  b7  = s1 ? t8  : t7;
            const float b8  = s1 ? t9  : t8,  b9  = s1 ? t10 : t9;
            const float b10 = s1 ? t11 : t10, b11 = s1 ? t12 : t11;
            const float b12 = s1 ? t13 : t12, b13 = s1 ? t14 : t13;
            const float b14 = s1 ? t15 : t14, b15 = s1 ? t16 : t15;
            const float b16 = s1 ? t17 : t16, b17 = s1 ? t18 : t17;
            const float b18 = s1 ? t19 : t18, b19 = s1 ? t20 : t19;
            const float b20 = s1 ? t21 : t20, b21 = s1 ? t22 : t21;
            const float b22 = s1 ? t23 : t22;
            float v[CC];
            v[0]  = s2 ? b2  : b0;  v[1]  = s2 ? b3  : b1;
            v[2]  = s2 ? b4  : b2;  v[3]  = s2 ? b5  : b3;
            v[4]  = s2 ? b6  : b4;  v[5]  = s2 ? b7  : b5;
            v[6]  = s2 ? b8  : b6;  v[7]  = s2 ? b9  : b7;
            v[8]  = s2 ? b10 : b8;  v[9]  = s2 ? b11 : b9;
            v[10] = s2 ? b12 : b10; v[11] = s2 ? b13 : b11;
            v[12] = s2 ? b14 : b12; v[13] = s2 ? b15 : b13;
            v[14] = s2 ? b16 : b14; v[15] = s2 ? b17 : b15;
            v[16] = s2 ? b18 : b16; v[17] = s2 ? b19 : b17;
            v[18] = s2 ? b20 : b18; v[19] = s2 ? b21 : b19;
            v[20] = s2 ? b22 : b20;
            // v[0..20] = logits x[gidx .. gidx+20]
            float m = v[0];
#pragma unroll
            for (int c = 1; c < CC; ++c) m = fmaxf(m, v[c]);
            float s = 0.f;
#pragma unroll
            for (int c = 0; c < CC; ++c) { v[c] = __expf(v[c] - m); s += v[c]; }
            const float inv = 1.0f / s;
#pragma unroll
            for (int cp = 0; cp < 10; ++cp) {
                __half2 hx = __floats2half2_rn(v[2*cp] * inv, v[2*cp+1] * inv);
                *(__half2*)(lbase + cp * PLANE_B) = hx;
            }
            __half2 hl = __floats2half2_rn(v[20] * inv, 0.f);  // pad slot = 0
            *(__half2*)(lbase + 10 * PLANE_B) = hl;
        } else {
            const __half2 z = __floats2half2_rn(0.f, 0.f);
#pragma unroll
            for (int cp = 0; cp < NP; ++cp)
                *(__half2*)(lbase + cp * PLANE_B) = z;
        }
    }
    __syncthreads();

    // ---- Phase 3: vertical blur, packed fp16, in place (rows 0..15) ----
    for (int t = tid; t < NTASK; t += 256) {
        const int cp  = t / PW;
        const int col = t - cp * PW;
        unsigned char* base = smem + cp * PLANE_B + col * 4;
        unsigned int v[PH];
#pragma unroll
        for (int r = 0; r < PH; ++r) v[r] = *(const unsigned int*)(base + r * ROW_B);
#pragma unroll
        for (int tt = 0; tt < TH; ++tt) {
            unsigned int s0 = pk_add(v[tt],     v[tt + 8]);
            unsigned int s1 = pk_add(v[tt + 1], v[tt + 7]);
            unsigned int s2 = pk_add(v[tt + 2], v[tt + 6]);
            unsigned int s3 = pk_add(v[tt + 3], v[tt + 5]);
            unsigned int acc = pk_mul(khp[0], s0);
            acc = pk_fma(khp[1], s1, acc);
            acc = pk_fma(khp[2], s2, acc);
            acc = pk_fma(khp[3], s3, acc);
            *(unsigned int*)(base + tt * ROW_B) = acc;
        }
    }
    __syncthreads();

    // ---- Phase 4: horizontal blur * sw, b128 rows, in place (cols 0..15) ----
    if (tid < TH * NP) {                   // 176 tasks
        const int h  = tid / NP;
        const int cp = tid - h * NP;
        unsigned char* base = smem + cp * PLANE_B + h * ROW_B;
        unsigned int v[PW];
#pragma unroll
        for (int k = 0; k < 6; ++k) {
            const uint4 q = *(const uint4*)(base + k * 16);
            v[4*k+0] = q.x; v[4*k+1] = q.y; v[4*k+2] = q.z; v[4*k+3] = q.w;
        }
        unsigned int o[TW];
#pragma unroll
        for (int wt = 0; wt < TW; ++wt) {
            unsigned int s0 = pk_add(v[wt],     v[wt + 8]);
            unsigned int s1 = pk_add(v[wt + 1], v[wt + 7]);
            unsigned int s2 = pk_add(v[wt + 2], v[wt + 6]);
            unsigned int s3 = pk_add(v[wt + 3], v[wt + 5]);
            unsigned int acc = pk_mul(kwp[0], s0);
            acc = pk_fma(kwp[1], s1, acc);
            acc = pk_fma(kwp[2], s2, acc);
            acc = pk_fma(kwp[3], s3, acc);
            o[wt] = acc;
        }
#pragma unroll
        for (int k = 0; k < 4; ++k) {
            uint4 wq;
            wq.x = o[4*k+0]; wq.y = o[4*k+1]; wq.z = o[4*k+2]; wq.w = o[4*k+3];
            *(uint4*)(base + k * 16) = wq;
        }
    }
    __syncthreads();

    // ---- Phase 5: out = unary + s, float4 I/O, planar b16 walk ----
    // s lives at planar rows 0..15 (h), cols 0..15 (wt). Walk per chunk:
    //   (px, even c<20) -> +2 ; (px, odd c) -> +(PLANE_B-2) ;
    //   (px, 20) -> (px+1, 0): +(4 - 10*PLANE_B).
    {
        const int gbase = ((b * Himg + h0) * Wimg + w0) * CC;
        for (int j = tid; j < NCHUNK5; j += 256) {
            const int hrow = j / RCHUNKS;
            const int qq   = j - hrow * RCHUNKS;
            const int f    = qq * 4;
            int px = f / 21;
            int c  = f - px * 21;
            int addr = (c >> 1) * PLANE_B + hrow * ROW_B + px * 4 + (c & 1) * 2;
            float sv[4];
#pragma unroll
            for (int i = 0; i < 4; ++i) {
                sv[i] = __half2float(*(const __half*)(smem + addr));
                const int wrap = (c == 20);
                const int odd  = c & 1;
                addr += wrap ? (4 - 10 * PLANE_B) : (odd ? (PLANE_B - 2) : 2);
                c = wrap ? 0 : c + 1;
            }
            const int g = gbase + hrow * (Wimg * CC) + f;
            const float4 u = *(const float4*)(unary + g);
            float4 o;
            o.x = u.x + sv[0]; o.y = u.y + sv[1];
            o.z = u.z + sv[2]; o.w = u.w + sv[3];
            *(float4*)(out + g) = o;
        }
    }
}

extern "C" void kernel_launch(void* const* d_in, const int* in_sizes, int n_in,
                              void* d_out, int out_size, void* d_ws, size_t ws_size,
                              hipStream_t stream) {
    const float* x         = (const float*)d_in[0];
    const float* spacings  = (const float*)d_in[1];
    const float* sw        = (const float*)d_in[2];
    const float* inv_theta = (const float*)d_in[3];
    float* out = (float*)d_out;
    float* ws  = (float*)d_ws;

    dim3 grid(Wimg / TW, Himg / TH, BB);   // 24 x 24 x 16 = 9216 blocks
    dim3 block(256);

    crf_iter_kernel<<<grid, block, 0, stream>>>(x,   x, out, spacings, inv_theta, sw);
    crf_iter_kernel<<<grid, block, 0, stream>>>(out, x, ws,  spacings, inv_theta, sw);
    crf_iter_kernel<<<grid, block, 0, stream>>>(ws,  x, out, spacings, inv_theta, sw);
    crf_iter_kernel<<<grid, block, 0, stream>>>(out, x, ws,  spacings, inv_theta, sw);
    crf_iter_kernel<<<grid, block, 0, stream>>>(ws,  x, out, spacings, inv_theta, sw);
}